// Round 7
// baseline (249.205 us; speedup 1.0000x reference)
//
#include <hip/hip_runtime.h>
#include <math.h>

#define BB 2
#define SS 2048
#define DD 1024
#define HH 16
#define HD 64

typedef short short8 __attribute__((ext_vector_type(8)));
typedef float floatx4 __attribute__((ext_vector_type(4)));
typedef float floatx16 __attribute__((ext_vector_type(16)));
typedef unsigned int uintx2 __attribute__((ext_vector_type(2)));

__device__ inline ushort f2bf_rne(float x) {
    union { float f; unsigned u; } v; v.f = x;
    unsigned r = v.u + 0x7FFFu + ((v.u >> 16) & 1u);
    return (ushort)(r >> 16);
}
__device__ inline unsigned cvt_pk_bf16(float lo, float hi) {
    unsigned r;
    asm("v_cvt_pk_bf16_f32 %0, %1, %2" : "=v"(r) : "v"(lo), "v"(hi));
    return r;
}
// pack 8 fp32 -> 8 bf16 (4x v_cvt_pk_bf16_f32)
__device__ inline short8 cvt8(float4 lo, float4 hi) {
    union { unsigned u[4]; short8 s; } t;
    t.u[0] = cvt_pk_bf16(lo.x, lo.y);
    t.u[1] = cvt_pk_bf16(lo.z, lo.w);
    t.u[2] = cvt_pk_bf16(hi.x, hi.y);
    t.u[3] = cvt_pk_bf16(hi.z, hi.w);
    return t.s;
}
// assemble PV A-frag from two permlane32_swap results: [x.lo, y.lo, x.hi, y.hi]
__device__ inline short8 mk_pf(uintx2 x, uintx2 y) {
    union { unsigned u[4]; short8 s; } t;
    t.u[0] = x[0]; t.u[1] = y[0]; t.u[2] = x[1]; t.u[3] = y[1];
    return t.s;
}

// async global -> LDS DMA, 16 B per lane (dest must be wave-linear: base + lane*16)
#define GLD16(gp, lp) __builtin_amdgcn_global_load_lds( \
    (const __attribute__((address_space(1))) void*)(gp), \
    (__attribute__((address_space(3))) void*)(lp), 16, 0, 0)

// ---------------- QKV GEMM: 128x128, FUSED fp32->bf16 staging, XCD-chunked grid ----------------
// Inputs X and W read directly in fp32; conversion (v_cvt_pk_bf16_f32) happens in
// registers during staging, so the ds_read/MFMA side stays bf16 and the separate
// convert_bf16 kernel (one full launch + ~100 MB of HBM traffic) disappears.
// 1-D grid 768; wg = (bid&7)*96 + bid/8: each XCD gets a contiguous (z,m)-chunk
// so A row-panels are fetched into exactly one L2.
__global__ __launch_bounds__(256, 3)
void qkv_gemm(const float* __restrict__ Xq, const float* __restrict__ Xk,
              const float* __restrict__ Xv,
              const float* __restrict__ Wq, const float* __restrict__ Wk,
              const float* __restrict__ Wv,
              const float* __restrict__ bq, const float* __restrict__ bk,
              const float* __restrict__ bv, const int* __restrict__ mask,
              ushort* __restrict__ Qo, ushort* __restrict__ Ko,
              ushort* __restrict__ Vo, float qscale)
{
    __shared__ __align__(16) ushort Alds[128][32];
    __shared__ __align__(16) ushort Blds[128][32];

    const int tid = threadIdx.x;

    // bijective XCD-chunk swizzle (768 % 8 == 0)
    const int wg  = (blockIdx.x & 7) * 96 + (blockIdx.x >> 3);
    const int z   = wg >> 8;            // 0..2
    const int rem = wg & 255;
    const int m0  = (rem >> 3) * 128;   // 32 m-blocks
    const int n0  = (rem & 7) * 128;    // 8 n-blocks

    const float* X    = (z == 0) ? Xq : (z == 1) ? Xk : Xv;
    const float* W    = (z == 0) ? Wq : (z == 1) ? Wk : Wv;
    const float* bias = (z == 0) ? bq : (z == 1) ? bk : bv;
    const float  osc  = (z == 0) ? qscale : 1.0f;

    const int lane = tid & 63;
    const int wave = tid >> 6;
    const int wr = wave >> 1;
    const int wc = wave & 1;
    const int lt = lane & 15;
    const int lq = lane >> 4;

    floatx4 acc[4][4];
#pragma unroll
    for (int mi = 0; mi < 4; ++mi)
#pragma unroll
        for (int ni = 0; ni < 4; ++ni) acc[mi][ni] = (floatx4)0.0f;

    const int srow = tid >> 1;          // 0..127
    const int sks  = (tid & 1) << 4;    // 0 or 16
    const float* gA = X + (size_t)(m0 + srow) * DD + sks;
    const float* gB = W + (size_t)(n0 + srow) * DD + sks;

    for (int k0 = 0; k0 < DD; k0 += 32) {
        // fp32 loads issued before the barrier so HBM latency overlaps prior MFMA
        const float4 a0 = *(const float4*)(gA + k0);
        const float4 a1 = *(const float4*)(gA + k0 + 4);
        const float4 a2 = *(const float4*)(gA + k0 + 8);
        const float4 a3 = *(const float4*)(gA + k0 + 12);
        const float4 b0 = *(const float4*)(gB + k0);
        const float4 b1 = *(const float4*)(gB + k0 + 4);
        const float4 b2 = *(const float4*)(gB + k0 + 8);
        const float4 b3 = *(const float4*)(gB + k0 + 12);

        __syncthreads();
        *(short8*)&Alds[srow][sks]     = cvt8(a0, a1);
        *(short8*)&Alds[srow][sks + 8] = cvt8(a2, a3);
        *(short8*)&Blds[srow][sks]     = cvt8(b0, b1);
        *(short8*)&Blds[srow][sks + 8] = cvt8(b2, b3);
        __syncthreads();

        short8 af[4], bf_[4];
#pragma unroll
        for (int mi = 0; mi < 4; ++mi)
            af[mi] = *(const short8*)&Alds[wr * 64 + mi * 16 + lt][lq * 8];
#pragma unroll
        for (int ni = 0; ni < 4; ++ni)
            bf_[ni] = *(const short8*)&Blds[wc * 64 + ni * 16 + lt][lq * 8];

#pragma unroll
        for (int mi = 0; mi < 4; ++mi)
#pragma unroll
            for (int ni = 0; ni < 4; ++ni)
                acc[mi][ni] = __builtin_amdgcn_mfma_f32_16x16x32_bf16(af[mi], bf_[ni], acc[mi][ni], 0, 0, 0);
    }

    float bbv[4];
#pragma unroll
    for (int ni = 0; ni < 4; ++ni) bbv[ni] = bias[n0 + wc * 64 + ni * 16 + lt];

    if (z == 2) {
        // V^T write, masked key rows zeroed so attention PV needs no mask.
#pragma unroll
        for (int mi = 0; mi < 4; ++mi) {
            const int mb  = m0 + wr * 64 + mi * 16 + lq * 4;
            const int bb_ = mb >> 11;
            const int s   = mb & (SS - 1);
            const int4 mm = *(const int4*)(mask + bb_ * SS + s);
            const float mf0 = (float)mm.x, mf1 = (float)mm.y;
            const float mf2 = (float)mm.z, mf3 = (float)mm.w;
#pragma unroll
            for (int ni = 0; ni < 4; ++ni) {
                const int n = n0 + wc * 64 + ni * 16 + lt;
                const int h = n >> 6;
                ushort4 pack;
                pack.x = f2bf_rne((acc[mi][ni][0] + bbv[ni]) * mf0);
                pack.y = f2bf_rne((acc[mi][ni][1] + bbv[ni]) * mf1);
                pack.z = f2bf_rne((acc[mi][ni][2] + bbv[ni]) * mf2);
                pack.w = f2bf_rne((acc[mi][ni][3] + bbv[ni]) * mf3);
                *(ushort4*)&Vo[(size_t)((bb_ * HH + h) * HD + (n & 63)) * SS + s] = pack;
            }
        }
    } else {
        // Q (scaled) or K (masked rows zeroed -> s=0 -> p=1, corrected in attn epilogue)
        ushort* C = z ? Ko : Qo;
#pragma unroll
        for (int mi = 0; mi < 4; ++mi) {
            const int mb  = m0 + wr * 64 + mi * 16 + lq * 4;
            const int bb_ = mb >> 11;
            const int s   = mb & (SS - 1);
            float mf[4] = {1.0f, 1.0f, 1.0f, 1.0f};
            if (z == 1) {
                const int4 mm = *(const int4*)(mask + bb_ * SS + s);
                mf[0] = (float)mm.x; mf[1] = (float)mm.y;
                mf[2] = (float)mm.z; mf[3] = (float)mm.w;
            }
#pragma unroll
            for (int ni = 0; ni < 4; ++ni) {
                const int n = n0 + wc * 64 + ni * 16 + lt;
                const int h = n >> 6;
#pragma unroll
                for (int r = 0; r < 4; ++r) {
                    C[(size_t)((bb_ * HH + h) * SS + (s + r)) * HD + (n & 63)] =
                        f2bf_rne((acc[mi][ni][r] + bbv[ni]) * osc * mf[r]);
                }
            }
        }
    }
}

// ---------------- MFMA flash attention: R4 structure (8 waves, 128-row q-block) + setprio ----------------
// 512 threads, grid 512 -> 2 blocks/CU x 8 waves = 4 waves/SIMD; measured 47.0 us
// in R4 (vs 51.2 for the 64-row variant: halving the q-block doubled per-CU K/V
// staging). s_setprio(1) wraps the MFMA clusters (T5, attn +4-7%).
#define LDV 68

__global__ __launch_bounds__(512, 4)
void attn_mfma(const ushort* __restrict__ Qb, const ushort* __restrict__ Kb,
               const ushort* __restrict__ Vt, const int* __restrict__ mask,
               ushort* __restrict__ Ob)
{
    __shared__ __align__(16) ushort KVlds[4][64][LDV];   // [0/1]=K dbuf, [2/3]=V dbuf
    __shared__ int Wsum[8];

    const int tid  = threadIdx.x;
    const int lane = tid & 63;
    const int wave = tid >> 6;     // 0..7
    const int ll   = lane & 31;
    const int hi   = lane >> 5;
    const int qh   = wave & 3;     // q-group owned (32 rows)
    const int ks   = wave >> 2;    // key sub-tile owned (32 keys)

    // XCD-locality swizzle (perf heuristic; any bid->XCD mapping stays correct)
    const int bid    = blockIdx.x;
    const int xcd    = bid & 7;
    const int slot   = bid >> 3;          // 0..63
    const int bhloc  = slot >> 4;         // 0..3
    const int qi     = slot & 15;         // 0..15
    const int bh     = xcd * 4 + bhloc;   // 0..31
    const int b      = bh >> 4;
    const int q0     = qi * 128;

    const size_t sbase = (size_t)bh * SS * HD;
    const size_t vbase = (size_t)bh * HD * SS;

    // masked-key count for the denominator correction (exact integer)
    {
        const int4 ma = *(const int4*)(mask + b * SS + tid * 4);
        int s = ma.x + ma.y + ma.z + ma.w;
#pragma unroll
        for (int w = 32; w >= 1; w >>= 1) s += __shfl_xor(s, w);
        if (lane == 0) Wsum[wave] = s;
    }

    short8 ones;
#pragma unroll
    for (int j = 0; j < 8; ++j) ones[j] = (short)0x3F80;   // bf16 1.0

    // Q B-frags for this wave's 32 q-rows: 4 dim-chunks, held in regs
    short8 qf[4];
    {
        const size_t qrow = sbase + (size_t)(q0 + qh * 32 + ll) * HD;
#pragma unroll
        for (int dc = 0; dc < 4; ++dc)
            qf[dc] = *(const short8*)(Qb + qrow + dc * 16 + hi * 8);
    }

    floatx16 oacc[2];
    oacc[0] = (floatx16)0.0f;
    oacc[1] = (floatx16)0.0f;
    floatx16 lacc = (floatx16)0.0f;

    const int srow = tid >> 3;          // 0..63
    const int sp8  = (tid & 7) << 3;    // 0..56

    short8 kr, vr;

    {   // prologue: tile 0 (one b128 K + one b128 V per thread)
        kr = *(const short8*)(Kb + sbase + (size_t)srow * HD + sp8);
        vr = *(const short8*)(Vt + vbase + (size_t)srow * SS + sp8);
        *(short8*)&KVlds[0][srow][sp8] = kr;
        *(short8*)&KVlds[2][srow][sp8] = vr;
    }

    const int NT = SS / 64;
    for (int kt = 0; kt < NT; ++kt) {
        const int cur = kt & 1;
        __syncthreads();

        if (kt + 1 < NT) {
            const int k0n = (kt + 1) * 64;
            kr = *(const short8*)(Kb + sbase + (size_t)(k0n + srow) * HD + sp8);
            vr = *(const short8*)(Vt + vbase + (size_t)srow * SS + k0n + sp8);
        }

        // ---- this wave's 32-key sub-tile K-frags
        short8 kf[4];
#pragma unroll
        for (int dc = 0; dc < 4; ++dc)
            kf[dc] = *(const short8*)&KVlds[cur][ks * 32 + ll][dc * 16 + hi * 8];

        // ---- S^T = K * Q^T over 64 dims
        floatx16 sacc = (floatx16)0.0f;
        __builtin_amdgcn_s_setprio(1);
#pragma unroll
        for (int dc = 0; dc < 4; ++dc)
            sacc = __builtin_amdgcn_mfma_f32_32x32x16_bf16(kf[dc], qf[dc], sacc, 0, 0, 0);
        __builtin_amdgcn_s_setprio(0);

        // ---- p = exp2(s), raw HW instruction (masked keys: s = 0 -> p = 1, corrected later)
        float p[16];
#pragma unroll
        for (int r = 0; r < 16; ++r) p[r] = __builtin_amdgcn_exp2f(sacc[r]);

        // ---- pack f32 P -> bf16 PV A-frags in-register
        const unsigned pk_a = cvt_pk_bf16(p[0],  p[1]);
        const unsigned pk_b = cvt_pk_bf16(p[2],  p[3]);
        const unsigned pk_c = cvt_pk_bf16(p[4],  p[5]);
        const unsigned pk_d = cvt_pk_bf16(p[6],  p[7]);
        const unsigned pk_e = cvt_pk_bf16(p[8],  p[9]);
        const unsigned pk_f = cvt_pk_bf16(p[10], p[11]);
        const unsigned pk_g = cvt_pk_bf16(p[12], p[13]);
        const unsigned pk_h = cvt_pk_bf16(p[14], p[15]);
        const uintx2 s1 = __builtin_amdgcn_permlane32_swap(pk_a, pk_c, false, false);
        const uintx2 s2 = __builtin_amdgcn_permlane32_swap(pk_b, pk_d, false, false);
        const uintx2 s3 = __builtin_amdgcn_permlane32_swap(pk_e, pk_g, false, false);
        const uintx2 s4 = __builtin_amdgcn_permlane32_swap(pk_f, pk_h, false, false);
        const short8 pf0 = mk_pf(s1, s2);   // keys ks*32 + 0..15
        const short8 pf1 = mk_pf(s3, s4);   // keys ks*32 + 16..31

        // ---- rowsum via ones-MFMA + PV from LDS V^T (masked V rows are zero)
        __builtin_amdgcn_s_setprio(1);
        lacc = __builtin_amdgcn_mfma_f32_32x32x16_bf16(pf0, ones, lacc, 0, 0, 0);
        lacc = __builtin_amdgcn_mfma_f32_32x32x16_bf16(pf1, ones, lacc, 0, 0, 0);
#pragma unroll
        for (int dn = 0; dn < 2; ++dn) {
            const short8 vf0 = *(const short8*)&KVlds[2 + cur][dn * 32 + ll][ks * 32 + hi * 8];
            const short8 vf1 = *(const short8*)&KVlds[2 + cur][dn * 32 + ll][ks * 32 + 16 + hi * 8];
            oacc[dn] = __builtin_amdgcn_mfma_f32_32x32x16_bf16(pf0, vf0, oacc[dn], 0, 0, 0);
            oacc[dn] = __builtin_amdgcn_mfma_f32_32x32x16_bf16(pf1, vf1, oacc[dn], 0, 0, 0);
        }
        __builtin_amdgcn_s_setprio(0);

        if (kt + 1 < NT) {
            const int nxt = cur ^ 1;
            *(short8*)&KVlds[nxt][srow][sp8]     = kr;
            *(short8*)&KVlds[2 + nxt][srow][sp8] = vr;
        }
    }

    // ---- combine key-split partials (ks=1 -> ks=0) via LDS aliased over KVlds.
    float* Cmb = (float*)&KVlds[0][0][0];
#pragma unroll
    for (int ph = 0; ph < 2; ++ph) {
        __syncthreads();
        if (ks == 1 && (qh >> 1) == ph) {
            const int sl = qh & 1;
#pragma unroll
            for (int dn = 0; dn < 2; ++dn)
#pragma unroll
                for (int r = 0; r < 16; ++r)
                    Cmb[((sl * 2 + dn) * 16 + r) * 64 + lane] = oacc[dn][r];
#pragma unroll
            for (int r = 0; r < 16; ++r)
                Cmb[4096 + (sl * 16 + r) * 64 + lane] = lacc[r];
        }
        __syncthreads();
        if (ks == 0 && (qh >> 1) == ph) {
            const int sl = qh & 1;
#pragma unroll
            for (int dn = 0; dn < 2; ++dn)
#pragma unroll
                for (int r = 0; r < 16; ++r)
                    oacc[dn][r] += Cmb[((sl * 2 + dn) * 16 + r) * 64 + lane];
#pragma unroll
            for (int r = 0; r < 16; ++r)
                lacc[r] += Cmb[4096 + (sl * 16 + r) * 64 + lane];
        }
    }

    // ---- epilogue (ks=0 waves): subtract masked count, normalize, write bf16 [B,S,D]
    if (ks == 0) {
        const int h = bh & 15;
        const float nmf = (float)(SS - (Wsum[0] + Wsum[1] + Wsum[2] + Wsum[3]
                                      + Wsum[4] + Wsum[5] + Wsum[6] + Wsum[7]));
        float linv[16];
#pragma unroll
        for (int r = 0; r < 16; ++r) linv[r] = 1.0f / (lacc[r] - nmf);
#pragma unroll
        for (int dn = 0; dn < 2; ++dn)
#pragma unroll
            for (int r = 0; r < 16; ++r) {
                const int q = q0 + qh * 32 + (r & 3) + 8 * (r >> 2) + 4 * hi;
                Ob[(size_t)(b * SS + q) * DD + h * HD + dn * 32 + ll] =
                    f2bf_rne(oacc[dn][r] * linv[r]);
            }
    }
}

// ---------------- O-projection GEMM: 128x64, A gload_lds bf16, B fused fp32->bf16 ----------------
__global__ __launch_bounds__(256, 3)
void o_gemm(const ushort* __restrict__ A, const float* __restrict__ B,
            const float* __restrict__ bias, float* __restrict__ out)
{
    __shared__ __align__(16) ushort sA[128][32];
    __shared__ __align__(16) ushort sB[64][32];

    const int tid  = threadIdx.x;
    const int lane = tid & 63;
    const int wave = tid >> 6;
    const int wr = wave >> 1;     // m half (64 rows)
    const int wc = wave & 1;      // n half (32 cols)
    const int lt = lane & 15;
    const int lq = lane >> 4;

    // bijective XCD-chunk swizzle (512 % 8 == 0): same-m n-blocks share an XCD
    const int wg = (blockIdx.x & 7) * 64 + (blockIdx.x >> 3);
    const int m0 = (wg >> 4) * 128;   // 32 m-blocks
    const int n0 = (wg & 15) * 64;    // 16 n-blocks

    floatx4 acc[4][2];
#pragma unroll
    for (int mi = 0; mi < 4; ++mi)
#pragma unroll
        for (int ni = 0; ni < 2; ++ni) acc[mi][ni] = (floatx4)0.0f;

    const int srow = tid >> 2;          // 0..63
    const int sc   = (tid & 3) << 3;    // 0,8,16,24
    const ushort* gA0 = A + (size_t)(m0 + srow) * DD + sc;
    const ushort* gA1 = A + (size_t)(m0 + 64 + srow) * DD + sc;
    const float*  gB  = B + (size_t)(n0 + srow) * DD + sc;

    for (int k0 = 0; k0 < DD; k0 += 32) {
        const float4 b0 = *(const float4*)(gB + k0);
        const float4 b1 = *(const float4*)(gB + k0 + 4);
        __syncthreads();
        GLD16(gA0 + k0, &sA[srow][sc]);
        GLD16(gA1 + k0, &sA[64 + srow][sc]);
        *(short8*)&sB[srow][sc] = cvt8(b0, b1);
        __syncthreads();

        short8 af[4], bf_[2];
#pragma unroll
        for (int mi = 0; mi < 4; ++mi)
            af[mi] = *(const short8*)&sA[wr * 64 + mi * 16 + lt][lq * 8];
#pragma unroll
        for (int ni = 0; ni < 2; ++ni)
            bf_[ni] = *(const short8*)&sB[wc * 32 + ni * 16 + lt][lq * 8];

#pragma unroll
        for (int mi = 0; mi < 4; ++mi)
#pragma unroll
            for (int ni = 0; ni < 2; ++ni)
                acc[mi][ni] = __builtin_amdgcn_mfma_f32_16x16x32_bf16(af[mi], bf_[ni], acc[mi][ni], 0, 0, 0);
    }

#pragma unroll
    for (int mi = 0; mi < 4; ++mi)
#pragma unroll
        for (int ni = 0; ni < 2; ++ni) {
            const int n = n0 + wc * 32 + ni * 16 + lt;
            const float bb = bias[n];
#pragma unroll
            for (int r = 0; r < 4; ++r) {
                const int m = m0 + wr * 64 + mi * 16 + lq * 4 + r;
                out[(size_t)m * DD + n] = acc[mi][ni][r] + bb;
            }
        }
}

extern "C" void kernel_launch(void* const* d_in, const int* in_sizes, int n_in,
                              void* d_out, int out_size, void* d_ws, size_t ws_size,
                              hipStream_t stream) {
    const float* xq   = (const float*)d_in[0];
    const float* xk   = (const float*)d_in[1];
    const float* xv   = (const float*)d_in[2];
    const int*   mask = (const int*)d_in[3];
    const float* wq   = (const float*)d_in[4];
    const float* bq   = (const float*)d_in[5];
    const float* wk   = (const float*)d_in[6];
    const float* bk   = (const float*)d_in[7];
    const float* wv   = (const float*)d_in[8];
    const float* bv   = (const float*)d_in[9];
    const float* wo   = (const float*)d_in[10];
    const float* bo   = (const float*)d_in[11];
    float* out = (float*)d_out;

    const size_t n = (size_t)BB * SS * DD;   // 4,194,304 elements

    // ws: Kb 8 MB, Vt 8 MB, Ob 8 MB (no bf16 input copies needed anymore).
    ushort* Kb = (ushort*)d_ws;
    ushort* Vt = Kb + n;
    ushort* Ob = Vt + n;

    // d_out: Qb in [0,8MB) — consumed by attn before o_gemm overwrites out.
    ushort* Qb = (ushort*)out;

    const float qscale = 0.125f * 1.44269504088896340736f;   // /sqrt(HD) * log2(e)

    qkv_gemm<<<dim3(768), 256, 0, stream>>>(xq, xk, xv, wq, wk, wv,
                                            bq, bk, bv, mask, Qb, Kb, Vt, qscale);

    attn_mfma<<<dim3(512), 512, 0, stream>>>(Qb, Kb, Vt, mask, Ob);

    o_gemm<<<dim3(512), 256, 0, stream>>>(Ob, wo, bo, out);
}

// Round 8
// 243.761 us; speedup vs baseline: 1.0223x; 1.0223x over previous
//
#include <hip/hip_runtime.h>
#include <math.h>

#define BB 2
#define SS 2048
#define DD 1024
#define HH 16
#define HD 64

typedef short short8 __attribute__((ext_vector_type(8)));
typedef float floatx4 __attribute__((ext_vector_type(4)));
typedef float floatx16 __attribute__((ext_vector_type(16)));
typedef unsigned int uintx2 __attribute__((ext_vector_type(2)));

__device__ inline ushort f2bf_rne(float x) {
    union { float f; unsigned u; } v; v.f = x;
    unsigned r = v.u + 0x7FFFu + ((v.u >> 16) & 1u);
    return (ushort)(r >> 16);
}
__device__ inline unsigned cvt_pk_bf16(float lo, float hi) {
    unsigned r;
    asm("v_cvt_pk_bf16_f32 %0, %1, %2" : "=v"(r) : "v"(lo), "v"(hi));
    return r;
}
// pack 8 fp32 -> 8 bf16 (4x v_cvt_pk_bf16_f32)
__device__ inline short8 cvt8(float4 lo, float4 hi) {
    union { unsigned u[4]; short8 s; } t;
    t.u[0] = cvt_pk_bf16(lo.x, lo.y);
    t.u[1] = cvt_pk_bf16(lo.z, lo.w);
    t.u[2] = cvt_pk_bf16(hi.x, hi.y);
    t.u[3] = cvt_pk_bf16(hi.z, hi.w);
    return t.s;
}
// assemble PV A-frag from two permlane32_swap results: [x.lo, y.lo, x.hi, y.hi]
__device__ inline short8 mk_pf(uintx2 x, uintx2 y) {
    union { unsigned u[4]; short8 s; } t;
    t.u[0] = x[0]; t.u[1] = y[0]; t.u[2] = x[1]; t.u[3] = y[1];
    return t.s;
}

// async global -> LDS DMA, 16 B per lane (dest must be wave-linear: base + lane*16)
#define GLD16(gp, lp) __builtin_amdgcn_global_load_lds( \
    (const __attribute__((address_space(1))) void*)(gp), \
    (__attribute__((address_space(3))) void*)(lp), 16, 0, 0)

// ---------------- QKV GEMM: 128x128, fused fp32->bf16, PIPELINED reg staging ----------------
// Staging regs for tile k+1 are loaded right after the store-barrier, so the
// ~900-cyc cold-HBM latency flies under the current tile's ds_read + 16 MFMA
// (R7 issued them immediately before the consuming ds_write: 88 us, all pipes
// idle). LDS padded [128][40] (legal again without gload_lds): row stride 80 B
// kills the 8-way fragment-read conflict of the linear [128][32] layout.
// XCD-chunked 1-D grid 768 keeps A row-panels in one L2.
#define LDK 40

__global__ __launch_bounds__(256, 3)
void qkv_gemm(const float* __restrict__ Xq, const float* __restrict__ Xk,
              const float* __restrict__ Xv,
              const float* __restrict__ Wq, const float* __restrict__ Wk,
              const float* __restrict__ Wv,
              const float* __restrict__ bq, const float* __restrict__ bk,
              const float* __restrict__ bv, const int* __restrict__ mask,
              ushort* __restrict__ Qo, ushort* __restrict__ Ko,
              ushort* __restrict__ Vo, float qscale)
{
    __shared__ __align__(16) ushort Alds[128][LDK];
    __shared__ __align__(16) ushort Blds[128][LDK];

    const int tid = threadIdx.x;

    // bijective XCD-chunk swizzle (768 % 8 == 0)
    const int wg  = (blockIdx.x & 7) * 96 + (blockIdx.x >> 3);
    const int z   = wg >> 8;            // 0..2
    const int rem = wg & 255;
    const int m0  = (rem >> 3) * 128;   // 32 m-blocks
    const int n0  = (rem & 7) * 128;    // 8 n-blocks

    const float* X    = (z == 0) ? Xq : (z == 1) ? Xk : Xv;
    const float* W    = (z == 0) ? Wq : (z == 1) ? Wk : Wv;
    const float* bias = (z == 0) ? bq : (z == 1) ? bk : bv;
    const float  osc  = (z == 0) ? qscale : 1.0f;

    const int lane = tid & 63;
    const int wave = tid >> 6;
    const int wr = wave >> 1;
    const int wc = wave & 1;
    const int lt = lane & 15;
    const int lq = lane >> 4;

    floatx4 acc[4][4];
#pragma unroll
    for (int mi = 0; mi < 4; ++mi)
#pragma unroll
        for (int ni = 0; ni < 4; ++ni) acc[mi][ni] = (floatx4)0.0f;

    const int srow = tid >> 1;          // 0..127
    const int sks  = (tid & 1) << 4;    // 0 or 16
    const float* gA = X + (size_t)(m0 + srow) * DD + sks;
    const float* gB = W + (size_t)(n0 + srow) * DD + sks;

    // prologue: load tile 0 into registers
    float4 a0 = *(const float4*)(gA);
    float4 a1 = *(const float4*)(gA + 4);
    float4 a2 = *(const float4*)(gA + 8);
    float4 a3 = *(const float4*)(gA + 12);
    float4 b0 = *(const float4*)(gB);
    float4 b1 = *(const float4*)(gB + 4);
    float4 b2 = *(const float4*)(gB + 8);
    float4 b3 = *(const float4*)(gB + 12);

    for (int k0 = 0; k0 < DD; k0 += 32) {
        __syncthreads();
        *(short8*)&Alds[srow][sks]     = cvt8(a0, a1);
        *(short8*)&Alds[srow][sks + 8] = cvt8(a2, a3);
        *(short8*)&Blds[srow][sks]     = cvt8(b0, b1);
        *(short8*)&Blds[srow][sks + 8] = cvt8(b2, b3);
        __syncthreads();

        // issue NEXT tile's loads now: in flight during ds_read + MFMA below
        if (k0 + 32 < DD) {
            a0 = *(const float4*)(gA + k0 + 32);
            a1 = *(const float4*)(gA + k0 + 36);
            a2 = *(const float4*)(gA + k0 + 40);
            a3 = *(const float4*)(gA + k0 + 44);
            b0 = *(const float4*)(gB + k0 + 32);
            b1 = *(const float4*)(gB + k0 + 36);
            b2 = *(const float4*)(gB + k0 + 40);
            b3 = *(const float4*)(gB + k0 + 44);
        }

        short8 af[4], bf_[4];
#pragma unroll
        for (int mi = 0; mi < 4; ++mi)
            af[mi] = *(const short8*)&Alds[wr * 64 + mi * 16 + lt][lq * 8];
#pragma unroll
        for (int ni = 0; ni < 4; ++ni)
            bf_[ni] = *(const short8*)&Blds[wc * 64 + ni * 16 + lt][lq * 8];

#pragma unroll
        for (int mi = 0; mi < 4; ++mi)
#pragma unroll
            for (int ni = 0; ni < 4; ++ni)
                acc[mi][ni] = __builtin_amdgcn_mfma_f32_16x16x32_bf16(af[mi], bf_[ni], acc[mi][ni], 0, 0, 0);
    }

    float bbv[4];
#pragma unroll
    for (int ni = 0; ni < 4; ++ni) bbv[ni] = bias[n0 + wc * 64 + ni * 16 + lt];

    if (z == 2) {
        // V^T write, masked key rows zeroed so attention PV needs no mask.
#pragma unroll
        for (int mi = 0; mi < 4; ++mi) {
            const int mb  = m0 + wr * 64 + mi * 16 + lq * 4;
            const int bb_ = mb >> 11;
            const int s   = mb & (SS - 1);
            const int4 mm = *(const int4*)(mask + bb_ * SS + s);
            const float mf0 = (float)mm.x, mf1 = (float)mm.y;
            const float mf2 = (float)mm.z, mf3 = (float)mm.w;
#pragma unroll
            for (int ni = 0; ni < 4; ++ni) {
                const int n = n0 + wc * 64 + ni * 16 + lt;
                const int h = n >> 6;
                ushort4 pack;
                pack.x = f2bf_rne((acc[mi][ni][0] + bbv[ni]) * mf0);
                pack.y = f2bf_rne((acc[mi][ni][1] + bbv[ni]) * mf1);
                pack.z = f2bf_rne((acc[mi][ni][2] + bbv[ni]) * mf2);
                pack.w = f2bf_rne((acc[mi][ni][3] + bbv[ni]) * mf3);
                *(ushort4*)&Vo[(size_t)((bb_ * HH + h) * HD + (n & 63)) * SS + s] = pack;
            }
        }
    } else {
        // Q (scaled) or K (masked rows zeroed -> s=0 -> p=1, corrected in attn epilogue)
        ushort* C = z ? Ko : Qo;
#pragma unroll
        for (int mi = 0; mi < 4; ++mi) {
            const int mb  = m0 + wr * 64 + mi * 16 + lq * 4;
            const int bb_ = mb >> 11;
            const int s   = mb & (SS - 1);
            float mf[4] = {1.0f, 1.0f, 1.0f, 1.0f};
            if (z == 1) {
                const int4 mm = *(const int4*)(mask + bb_ * SS + s);
                mf[0] = (float)mm.x; mf[1] = (float)mm.y;
                mf[2] = (float)mm.z; mf[3] = (float)mm.w;
            }
#pragma unroll
            for (int ni = 0; ni < 4; ++ni) {
                const int n = n0 + wc * 64 + ni * 16 + lt;
                const int h = n >> 6;
#pragma unroll
                for (int r = 0; r < 4; ++r) {
                    C[(size_t)((bb_ * HH + h) * SS + (s + r)) * HD + (n & 63)] =
                        f2bf_rne((acc[mi][ni][r] + bbv[ni]) * osc * mf[r]);
                }
            }
        }
    }
}

// ---------------- MFMA flash attention: R4 structure (8 waves, 128-row q-block) + setprio ----------------
#define LDV 68

__global__ __launch_bounds__(512, 4)
void attn_mfma(const ushort* __restrict__ Qb, const ushort* __restrict__ Kb,
               const ushort* __restrict__ Vt, const int* __restrict__ mask,
               ushort* __restrict__ Ob)
{
    __shared__ __align__(16) ushort KVlds[4][64][LDV];   // [0/1]=K dbuf, [2/3]=V dbuf
    __shared__ int Wsum[8];

    const int tid  = threadIdx.x;
    const int lane = tid & 63;
    const int wave = tid >> 6;     // 0..7
    const int ll   = lane & 31;
    const int hi   = lane >> 5;
    const int qh   = wave & 3;     // q-group owned (32 rows)
    const int ks   = wave >> 2;    // key sub-tile owned (32 keys)

    // XCD-locality swizzle (perf heuristic; any bid->XCD mapping stays correct)
    const int bid    = blockIdx.x;
    const int xcd    = bid & 7;
    const int slot   = bid >> 3;          // 0..63
    const int bhloc  = slot >> 4;         // 0..3
    const int qi     = slot & 15;         // 0..15
    const int bh     = xcd * 4 + bhloc;   // 0..31
    const int b      = bh >> 4;
    const int q0     = qi * 128;

    const size_t sbase = (size_t)bh * SS * HD;
    const size_t vbase = (size_t)bh * HD * SS;

    // masked-key count for the denominator correction (exact integer)
    {
        const int4 ma = *(const int4*)(mask + b * SS + tid * 4);
        int s = ma.x + ma.y + ma.z + ma.w;
#pragma unroll
        for (int w = 32; w >= 1; w >>= 1) s += __shfl_xor(s, w);
        if (lane == 0) Wsum[wave] = s;
    }

    short8 ones;
#pragma unroll
    for (int j = 0; j < 8; ++j) ones[j] = (short)0x3F80;   // bf16 1.0

    // Q B-frags for this wave's 32 q-rows: 4 dim-chunks, held in regs
    short8 qf[4];
    {
        const size_t qrow = sbase + (size_t)(q0 + qh * 32 + ll) * HD;
#pragma unroll
        for (int dc = 0; dc < 4; ++dc)
            qf[dc] = *(const short8*)(Qb + qrow + dc * 16 + hi * 8);
    }

    floatx16 oacc[2];
    oacc[0] = (floatx16)0.0f;
    oacc[1] = (floatx16)0.0f;
    floatx16 lacc = (floatx16)0.0f;

    const int srow = tid >> 3;          // 0..63
    const int sp8  = (tid & 7) << 3;    // 0..56

    short8 kr, vr;

    {   // prologue: tile 0 (one b128 K + one b128 V per thread)
        kr = *(const short8*)(Kb + sbase + (size_t)srow * HD + sp8);
        vr = *(const short8*)(Vt + vbase + (size_t)srow * SS + sp8);
        *(short8*)&KVlds[0][srow][sp8] = kr;
        *(short8*)&KVlds[2][srow][sp8] = vr;
    }

    const int NT = SS / 64;
    for (int kt = 0; kt < NT; ++kt) {
        const int cur = kt & 1;
        __syncthreads();

        if (kt + 1 < NT) {
            const int k0n = (kt + 1) * 64;
            kr = *(const short8*)(Kb + sbase + (size_t)(k0n + srow) * HD + sp8);
            vr = *(const short8*)(Vt + vbase + (size_t)srow * SS + k0n + sp8);
        }

        // ---- this wave's 32-key sub-tile K-frags
        short8 kf[4];
#pragma unroll
        for (int dc = 0; dc < 4; ++dc)
            kf[dc] = *(const short8*)&KVlds[cur][ks * 32 + ll][dc * 16 + hi * 8];

        // ---- S^T = K * Q^T over 64 dims
        floatx16 sacc = (floatx16)0.0f;
        __builtin_amdgcn_s_setprio(1);
#pragma unroll
        for (int dc = 0; dc < 4; ++dc)
            sacc = __builtin_amdgcn_mfma_f32_32x32x16_bf16(kf[dc], qf[dc], sacc, 0, 0, 0);
        __builtin_amdgcn_s_setprio(0);

        // ---- p = exp2(s), raw HW instruction (masked keys: s = 0 -> p = 1, corrected later)
        float p[16];
#pragma unroll
        for (int r = 0; r < 16; ++r) p[r] = __builtin_amdgcn_exp2f(sacc[r]);

        // ---- pack f32 P -> bf16 PV A-frags in-register
        const unsigned pk_a = cvt_pk_bf16(p[0],  p[1]);
        const unsigned pk_b = cvt_pk_bf16(p[2],  p[3]);
        const unsigned pk_c = cvt_pk_bf16(p[4],  p[5]);
        const unsigned pk_d = cvt_pk_bf16(p[6],  p[7]);
        const unsigned pk_e = cvt_pk_bf16(p[8],  p[9]);
        const unsigned pk_f = cvt_pk_bf16(p[10], p[11]);
        const unsigned pk_g = cvt_pk_bf16(p[12], p[13]);
        const unsigned pk_h = cvt_pk_bf16(p[14], p[15]);
        const uintx2 s1 = __builtin_amdgcn_permlane32_swap(pk_a, pk_c, false, false);
        const uintx2 s2 = __builtin_amdgcn_permlane32_swap(pk_b, pk_d, false, false);
        const uintx2 s3 = __builtin_amdgcn_permlane32_swap(pk_e, pk_g, false, false);
        const uintx2 s4 = __builtin_amdgcn_permlane32_swap(pk_f, pk_h, false, false);
        const short8 pf0 = mk_pf(s1, s2);   // keys ks*32 + 0..15
        const short8 pf1 = mk_pf(s3, s4);   // keys ks*32 + 16..31

        // ---- rowsum via ones-MFMA + PV from LDS V^T (masked V rows are zero)
        __builtin_amdgcn_s_setprio(1);
        lacc = __builtin_amdgcn_mfma_f32_32x32x16_bf16(pf0, ones, lacc, 0, 0, 0);
        lacc = __builtin_amdgcn_mfma_f32_32x32x16_bf16(pf1, ones, lacc, 0, 0, 0);
#pragma unroll
        for (int dn = 0; dn < 2; ++dn) {
            const short8 vf0 = *(const short8*)&KVlds[2 + cur][dn * 32 + ll][ks * 32 + hi * 8];
            const short8 vf1 = *(const short8*)&KVlds[2 + cur][dn * 32 + ll][ks * 32 + 16 + hi * 8];
            oacc[dn] = __builtin_amdgcn_mfma_f32_32x32x16_bf16(pf0, vf0, oacc[dn], 0, 0, 0);
            oacc[dn] = __builtin_amdgcn_mfma_f32_32x32x16_bf16(pf1, vf1, oacc[dn], 0, 0, 0);
        }
        __builtin_amdgcn_s_setprio(0);

        if (kt + 1 < NT) {
            const int nxt = cur ^ 1;
            *(short8*)&KVlds[nxt][srow][sp8]     = kr;
            *(short8*)&KVlds[2 + nxt][srow][sp8] = vr;
        }
    }

    // ---- combine key-split partials (ks=1 -> ks=0) via LDS aliased over KVlds.
    float* Cmb = (float*)&KVlds[0][0][0];
#pragma unroll
    for (int ph = 0; ph < 2; ++ph) {
        __syncthreads();
        if (ks == 1 && (qh >> 1) == ph) {
            const int sl = qh & 1;
#pragma unroll
            for (int dn = 0; dn < 2; ++dn)
#pragma unroll
                for (int r = 0; r < 16; ++r)
                    Cmb[((sl * 2 + dn) * 16 + r) * 64 + lane] = oacc[dn][r];
#pragma unroll
            for (int r = 0; r < 16; ++r)
                Cmb[4096 + (sl * 16 + r) * 64 + lane] = lacc[r];
        }
        __syncthreads();
        if (ks == 0 && (qh >> 1) == ph) {
            const int sl = qh & 1;
#pragma unroll
            for (int dn = 0; dn < 2; ++dn)
#pragma unroll
                for (int r = 0; r < 16; ++r)
                    oacc[dn][r] += Cmb[((sl * 2 + dn) * 16 + r) * 64 + lane];
#pragma unroll
            for (int r = 0; r < 16; ++r)
                lacc[r] += Cmb[4096 + (sl * 16 + r) * 64 + lane];
        }
    }

    // ---- epilogue (ks=0 waves): subtract masked count, normalize, write bf16 [B,S,D]
    if (ks == 0) {
        const int h = bh & 15;
        const float nmf = (float)(SS - (Wsum[0] + Wsum[1] + Wsum[2] + Wsum[3]
                                      + Wsum[4] + Wsum[5] + Wsum[6] + Wsum[7]));
        float linv[16];
#pragma unroll
        for (int r = 0; r < 16; ++r) linv[r] = 1.0f / (lacc[r] - nmf);
#pragma unroll
        for (int dn = 0; dn < 2; ++dn)
#pragma unroll
            for (int r = 0; r < 16; ++r) {
                const int q = q0 + qh * 32 + (r & 3) + 8 * (r >> 2) + 4 * hi;
                Ob[(size_t)(b * SS + q) * DD + h * HD + dn * 32 + ll] =
                    f2bf_rne(oacc[dn][r] * linv[r]);
            }
    }
}

// ---------------- O-projection GEMM: 128x64, A gload_lds bf16, B fused fp32 (pipelined) ----------------
__global__ __launch_bounds__(256, 3)
void o_gemm(const ushort* __restrict__ A, const float* __restrict__ B,
            const float* __restrict__ bias, float* __restrict__ out)
{
    __shared__ __align__(16) ushort sA[128][32];    // gload_lds: must stay linear
    __shared__ __align__(16) ushort sB[64][LDK];    // reg-staged: padded

    const int tid  = threadIdx.x;
    const int lane = tid & 63;
    const int wave = tid >> 6;
    const int wr = wave >> 1;     // m half (64 rows)
    const int wc = wave & 1;      // n half (32 cols)
    const int lt = lane & 15;
    const int lq = lane >> 4;

    // bijective XCD-chunk swizzle (512 % 8 == 0): same-m n-blocks share an XCD
    const int wg = (blockIdx.x & 7) * 64 + (blockIdx.x >> 3);
    const int m0 = (wg >> 4) * 128;   // 32 m-blocks
    const int n0 = (wg & 15) * 64;    // 16 n-blocks

    floatx4 acc[4][2];
#pragma unroll
    for (int mi = 0; mi < 4; ++mi)
#pragma unroll
        for (int ni = 0; ni < 2; ++ni) acc[mi][ni] = (floatx4)0.0f;

    const int srow = tid >> 2;          // 0..63
    const int sc   = (tid & 3) << 3;    // 0,8,16,24
    const ushort* gA0 = A + (size_t)(m0 + srow) * DD + sc;
    const ushort* gA1 = A + (size_t)(m0 + 64 + srow) * DD + sc;
    const float*  gB  = B + (size_t)(n0 + srow) * DD + sc;

    float4 b0 = *(const float4*)(gB);
    float4 b1 = *(const float4*)(gB + 4);

    for (int k0 = 0; k0 < DD; k0 += 32) {
        __syncthreads();
        GLD16(gA0 + k0, &sA[srow][sc]);
        GLD16(gA1 + k0, &sA[64 + srow][sc]);
        *(short8*)&sB[srow][sc] = cvt8(b0, b1);
        __syncthreads();

        if (k0 + 32 < DD) {
            b0 = *(const float4*)(gB + k0 + 32);
            b1 = *(const float4*)(gB + k0 + 36);
        }

        short8 af[4], bf_[2];
#pragma unroll
        for (int mi = 0; mi < 4; ++mi)
            af[mi] = *(const short8*)&sA[wr * 64 + mi * 16 + lt][lq * 8];
#pragma unroll
        for (int ni = 0; ni < 2; ++ni)
            bf_[ni] = *(const short8*)&sB[wc * 32 + ni * 16 + lt][lq * 8];

#pragma unroll
        for (int mi = 0; mi < 4; ++mi)
#pragma unroll
            for (int ni = 0; ni < 2; ++ni)
                acc[mi][ni] = __builtin_amdgcn_mfma_f32_16x16x32_bf16(af[mi], bf_[ni], acc[mi][ni], 0, 0, 0);
    }

#pragma unroll
    for (int mi = 0; mi < 4; ++mi)
#pragma unroll
        for (int ni = 0; ni < 2; ++ni) {
            const int n = n0 + wc * 32 + ni * 16 + lt;
            const float bb = bias[n];
#pragma unroll
            for (int r = 0; r < 4; ++r) {
                const int m = m0 + wr * 64 + mi * 16 + lq * 4 + r;
                out[(size_t)m * DD + n] = acc[mi][ni][r] + bb;
            }
        }
}

extern "C" void kernel_launch(void* const* d_in, const int* in_sizes, int n_in,
                              void* d_out, int out_size, void* d_ws, size_t ws_size,
                              hipStream_t stream) {
    const float* xq   = (const float*)d_in[0];
    const float* xk   = (const float*)d_in[1];
    const float* xv   = (const float*)d_in[2];
    const int*   mask = (const int*)d_in[3];
    const float* wq   = (const float*)d_in[4];
    const float* bq   = (const float*)d_in[5];
    const float* wk   = (const float*)d_in[6];
    const float* bk   = (const float*)d_in[7];
    const float* wv   = (const float*)d_in[8];
    const float* bv   = (const float*)d_in[9];
    const float* wo   = (const float*)d_in[10];
    const float* bo   = (const float*)d_in[11];
    float* out = (float*)d_out;

    const size_t n = (size_t)BB * SS * DD;   // 4,194,304 elements

    // ws: Kb 8 MB, Vt 8 MB, Ob 8 MB.
    ushort* Kb = (ushort*)d_ws;
    ushort* Vt = Kb + n;
    ushort* Ob = Vt + n;

    // d_out: Qb in [0,8MB) — consumed by attn before o_gemm overwrites out.
    ushort* Qb = (ushort*)out;

    const float qscale = 0.125f * 1.44269504088896340736f;   // /sqrt(HD) * log2(e)

    qkv_gemm<<<dim3(768), 256, 0, stream>>>(xq, xk, xv, wq, wk, wv,
                                            bq, bk, bv, mask, Qb, Kb, Vt, qscale);

    attn_mfma<<<dim3(512), 512, 0, stream>>>(Qb, Kb, Vt, mask, Ob);

    o_gemm<<<dim3(512), 256, 0, stream>>>(Ob, wo, bo, out);
}

// Round 9
// 212.702 us; speedup vs baseline: 1.1716x; 1.1460x over previous
//
#include <hip/hip_runtime.h>
#include <math.h>

#define BB 2
#define SS 2048
#define DD 1024
#define HH 16
#define HD 64

typedef short short8 __attribute__((ext_vector_type(8)));
typedef float floatx4 __attribute__((ext_vector_type(4)));
typedef float floatx16 __attribute__((ext_vector_type(16)));
typedef unsigned int uintx2 __attribute__((ext_vector_type(2)));

__device__ inline ushort f2bf_rne(float x) {
    union { float f; unsigned u; } v; v.f = x;
    unsigned r = v.u + 0x7FFFu + ((v.u >> 16) & 1u);
    return (ushort)(r >> 16);
}
__device__ inline unsigned cvt_pk_bf16(float lo, float hi) {
    unsigned r;
    asm("v_cvt_pk_bf16_f32 %0, %1, %2" : "=v"(r) : "v"(lo), "v"(hi));
    return r;
}
// assemble PV A-frag from two permlane32_swap results: [x.lo, y.lo, x.hi, y.hi]
__device__ inline short8 mk_pf(uintx2 x, uintx2 y) {
    union { unsigned u[4]; short8 s; } t;
    t.u[0] = x[0]; t.u[1] = y[0]; t.u[2] = x[1]; t.u[3] = y[1];
    return t.s;
}

// async global -> LDS DMA, 16 B per lane (dest must be wave-linear: base + lane*16)
#define GLD16(gp, lp) __builtin_amdgcn_global_load_lds( \
    (const __attribute__((address_space(1))) void*)(gp), \
    (__attribute__((address_space(3))) void*)(lp), 16, 0, 0)

// ---------------- streaming fp32 -> bf16 conversion ----------------
// Separate kernel is MEASURED-faster than fusing the convert into the GEMMs
// (R6 217.6 us vs R7/R8 244-249): bf16 staging lets the GEMMs use
// global_load_lds (async DMA, latency-hidden) while this kernel runs at
// streaming BW. Do not re-fuse without new evidence.
__global__ __launch_bounds__(256)
void convert_bf16(const float* __restrict__ xq, const float* __restrict__ xk,
                  const float* __restrict__ xv,
                  const float* __restrict__ wq, const float* __restrict__ wk,
                  const float* __restrict__ wv, const float* __restrict__ wo,
                  ushort* __restrict__ Xq, ushort* __restrict__ Xk,
                  ushort* __restrict__ Xv,
                  ushort* __restrict__ Wq, ushort* __restrict__ Wk,
                  ushort* __restrict__ Wv, ushort* __restrict__ Wo)
{
    const int z = blockIdx.z;
    const size_t i = ((size_t)blockIdx.x * 256 + threadIdx.x) * 8;

    const float* src;
    ushort* dst;
    size_t off;
    if (z < 3) {
        src = (z == 0) ? xq : (z == 1) ? xk : xv;
        dst = (z == 0) ? Xq : (z == 1) ? Xk : Xv;
        off = i;
    } else {
        const int seg = (int)(i >> 20);
        off = i & ((1u << 20) - 1);
        src = (seg == 0) ? wq : (seg == 1) ? wk : (seg == 2) ? wv : wo;
        dst = (seg == 0) ? Wq : (seg == 1) ? Wk : (seg == 2) ? Wv : Wo;
    }
    float x[8];
    *(float4*)&x[0] = *(const float4*)(src + off);
    *(float4*)&x[4] = *(const float4*)(src + off + 4);
    short8 h8;
#pragma unroll
    for (int j = 0; j < 8; ++j) h8[j] = (short)f2bf_rne(x[j]);
    *(short8*)&dst[off] = h8;
}

// ---------------- QKV GEMM: 128x128, gload_lds staging, XCD-chunked grid ----------------
// 1-D grid 768; wg = (bid&7)*96 + bid/8: each XCD gets a contiguous (z,m)-chunk
// so all 8 n-blocks sharing an A row-panel run on ONE XCD (A fetched into one L2).
// LDS [128][32] linear (gload_lds requires wave-linear dest). Direct C stores
// (R5's LDS-transposed epilogue measured slower).
__global__ __launch_bounds__(256, 3)
void qkv_gemm(const ushort* __restrict__ Xq, const ushort* __restrict__ Xk,
              const ushort* __restrict__ Xv,
              const ushort* __restrict__ Wq, const ushort* __restrict__ Wk,
              const ushort* __restrict__ Wv,
              const float* __restrict__ bq, const float* __restrict__ bk,
              const float* __restrict__ bv, const int* __restrict__ mask,
              ushort* __restrict__ Qo, ushort* __restrict__ Ko,
              ushort* __restrict__ Vo, float qscale)
{
    __shared__ __align__(16) ushort Alds[128][32];
    __shared__ __align__(16) ushort Blds[128][32];

    const int tid = threadIdx.x;

    // bijective XCD-chunk swizzle (768 % 8 == 0)
    const int wg  = (blockIdx.x & 7) * 96 + (blockIdx.x >> 3);
    const int z   = wg >> 8;            // 0..2
    const int rem = wg & 255;
    const int m0  = (rem >> 3) * 128;   // 32 m-blocks
    const int n0  = (rem & 7) * 128;    // 8 n-blocks

    const ushort* X    = (z == 0) ? Xq : (z == 1) ? Xk : Xv;
    const ushort* W    = (z == 0) ? Wq : (z == 1) ? Wk : Wv;
    const float*  bias = (z == 0) ? bq : (z == 1) ? bk : bv;
    const float   osc  = (z == 0) ? qscale : 1.0f;

    const int lane = tid & 63;
    const int wave = tid >> 6;
    const int wr = wave >> 1;
    const int wc = wave & 1;
    const int lt = lane & 15;
    const int lq = lane >> 4;

    floatx4 acc[4][4];
#pragma unroll
    for (int mi = 0; mi < 4; ++mi)
#pragma unroll
        for (int ni = 0; ni < 4; ++ni) acc[mi][ni] = (floatx4)0.0f;

    const int srow = tid >> 2;          // 0..63
    const int sc   = (tid & 3) << 3;    // ushort col: 0,8,16,24
    const ushort* gA0 = X + (size_t)(m0 + srow) * DD + sc;
    const ushort* gA1 = X + (size_t)(m0 + 64 + srow) * DD + sc;
    const ushort* gB0 = W + (size_t)(n0 + srow) * DD + sc;
    const ushort* gB1 = W + (size_t)(n0 + 64 + srow) * DD + sc;

    for (int k0 = 0; k0 < DD; k0 += 32) {
        __syncthreads();
        GLD16(gA0 + k0, &Alds[srow][sc]);
        GLD16(gA1 + k0, &Alds[64 + srow][sc]);
        GLD16(gB0 + k0, &Blds[srow][sc]);
        GLD16(gB1 + k0, &Blds[64 + srow][sc]);
        __syncthreads();

        short8 af[4], bf_[4];
#pragma unroll
        for (int mi = 0; mi < 4; ++mi)
            af[mi] = *(const short8*)&Alds[wr * 64 + mi * 16 + lt][lq * 8];
#pragma unroll
        for (int ni = 0; ni < 4; ++ni)
            bf_[ni] = *(const short8*)&Blds[wc * 64 + ni * 16 + lt][lq * 8];

#pragma unroll
        for (int mi = 0; mi < 4; ++mi)
#pragma unroll
            for (int ni = 0; ni < 4; ++ni)
                acc[mi][ni] = __builtin_amdgcn_mfma_f32_16x16x32_bf16(af[mi], bf_[ni], acc[mi][ni], 0, 0, 0);
    }

    float bbv[4];
#pragma unroll
    for (int ni = 0; ni < 4; ++ni) bbv[ni] = bias[n0 + wc * 64 + ni * 16 + lt];

    if (z == 2) {
        // V^T write, masked key rows zeroed so attention PV needs no mask.
#pragma unroll
        for (int mi = 0; mi < 4; ++mi) {
            const int mb  = m0 + wr * 64 + mi * 16 + lq * 4;
            const int bb_ = mb >> 11;
            const int s   = mb & (SS - 1);
            const int4 mm = *(const int4*)(mask + bb_ * SS + s);
            const float mf0 = (float)mm.x, mf1 = (float)mm.y;
            const float mf2 = (float)mm.z, mf3 = (float)mm.w;
#pragma unroll
            for (int ni = 0; ni < 4; ++ni) {
                const int n = n0 + wc * 64 + ni * 16 + lt;
                const int h = n >> 6;
                ushort4 pack;
                pack.x = f2bf_rne((acc[mi][ni][0] + bbv[ni]) * mf0);
                pack.y = f2bf_rne((acc[mi][ni][1] + bbv[ni]) * mf1);
                pack.z = f2bf_rne((acc[mi][ni][2] + bbv[ni]) * mf2);
                pack.w = f2bf_rne((acc[mi][ni][3] + bbv[ni]) * mf3);
                *(ushort4*)&Vo[(size_t)((bb_ * HH + h) * HD + (n & 63)) * SS + s] = pack;
            }
        }
    } else {
        // Q (scaled) or K (masked rows zeroed -> s=0 -> p=1, corrected in attn epilogue)
        ushort* C = z ? Ko : Qo;
#pragma unroll
        for (int mi = 0; mi < 4; ++mi) {
            const int mb  = m0 + wr * 64 + mi * 16 + lq * 4;
            const int bb_ = mb >> 11;
            const int s   = mb & (SS - 1);
            float mf[4] = {1.0f, 1.0f, 1.0f, 1.0f};
            if (z == 1) {
                const int4 mm = *(const int4*)(mask + bb_ * SS + s);
                mf[0] = (float)mm.x; mf[1] = (float)mm.y;
                mf[2] = (float)mm.z; mf[3] = (float)mm.w;
            }
#pragma unroll
            for (int ni = 0; ni < 4; ++ni) {
                const int n = n0 + wc * 64 + ni * 16 + lt;
                const int h = n >> 6;
#pragma unroll
                for (int r = 0; r < 4; ++r) {
                    C[(size_t)((bb_ * HH + h) * SS + (s + r)) * HD + (n & 63)] =
                        f2bf_rne((acc[mi][ni][r] + bbv[ni]) * osc * mf[r]);
                }
            }
        }
    }
}

// ---------------- MFMA flash attention: 8 waves, 128-row q-block (measured-best) + setprio ----------------
// 512 threads, grid 512 -> 2 blocks/CU x 8 waves = 4 waves/SIMD; this structure
// measured 47.0 us (R4) vs 51.2 for the 64-row/4-wave variant (R5/R6: halving
// the q-block doubles per-CU K/V staging). Swapped QK^T 32x32, in-register
// softmax (cvt_pk+permlane32_swap), mask pre-folded (zeroed K/V rows; epilogue
// subtracts masked count), raw v_exp_f32.
#define LDV 68

__global__ __launch_bounds__(512, 4)
void attn_mfma(const ushort* __restrict__ Qb, const ushort* __restrict__ Kb,
               const ushort* __restrict__ Vt, const int* __restrict__ mask,
               ushort* __restrict__ Ob)
{
    __shared__ __align__(16) ushort KVlds[4][64][LDV];   // [0/1]=K dbuf, [2/3]=V dbuf
    __shared__ int Wsum[8];

    const int tid  = threadIdx.x;
    const int lane = tid & 63;
    const int wave = tid >> 6;     // 0..7
    const int ll   = lane & 31;
    const int hi   = lane >> 5;
    const int qh   = wave & 3;     // q-group owned (32 rows)
    const int ks   = wave >> 2;    // key sub-tile owned (32 keys)

    // XCD-locality swizzle (perf heuristic; any bid->XCD mapping stays correct)
    const int bid    = blockIdx.x;
    const int xcd    = bid & 7;
    const int slot   = bid >> 3;          // 0..63
    const int bhloc  = slot >> 4;         // 0..3
    const int qi     = slot & 15;         // 0..15
    const int bh     = xcd * 4 + bhloc;   // 0..31
    const int b      = bh >> 4;
    const int q0     = qi * 128;

    const size_t sbase = (size_t)bh * SS * HD;
    const size_t vbase = (size_t)bh * HD * SS;

    // masked-key count for the denominator correction (exact integer)
    {
        const int4 ma = *(const int4*)(mask + b * SS + tid * 4);
        int s = ma.x + ma.y + ma.z + ma.w;
#pragma unroll
        for (int w = 32; w >= 1; w >>= 1) s += __shfl_xor(s, w);
        if (lane == 0) Wsum[wave] = s;
    }

    short8 ones;
#pragma unroll
    for (int j = 0; j < 8; ++j) ones[j] = (short)0x3F80;   // bf16 1.0

    // Q B-frags for this wave's 32 q-rows: 4 dim-chunks, held in regs
    short8 qf[4];
    {
        const size_t qrow = sbase + (size_t)(q0 + qh * 32 + ll) * HD;
#pragma unroll
        for (int dc = 0; dc < 4; ++dc)
            qf[dc] = *(const short8*)(Qb + qrow + dc * 16 + hi * 8);
    }

    floatx16 oacc[2];
    oacc[0] = (floatx16)0.0f;
    oacc[1] = (floatx16)0.0f;
    floatx16 lacc = (floatx16)0.0f;

    const int srow = tid >> 3;          // 0..63
    const int sp8  = (tid & 7) << 3;    // 0..56

    short8 kr, vr;

    {   // prologue: tile 0 (one b128 K + one b128 V per thread)
        kr = *(const short8*)(Kb + sbase + (size_t)srow * HD + sp8);
        vr = *(const short8*)(Vt + vbase + (size_t)srow * SS + sp8);
        *(short8*)&KVlds[0][srow][sp8] = kr;
        *(short8*)&KVlds[2][srow][sp8] = vr;
    }

    const int NT = SS / 64;
    for (int kt = 0; kt < NT; ++kt) {
        const int cur = kt & 1;
        __syncthreads();

        if (kt + 1 < NT) {
            const int k0n = (kt + 1) * 64;
            kr = *(const short8*)(Kb + sbase + (size_t)(k0n + srow) * HD + sp8);
            vr = *(const short8*)(Vt + vbase + (size_t)srow * SS + k0n + sp8);
        }

        // ---- this wave's 32-key sub-tile K-frags
        short8 kf[4];
#pragma unroll
        for (int dc = 0; dc < 4; ++dc)
            kf[dc] = *(const short8*)&KVlds[cur][ks * 32 + ll][dc * 16 + hi * 8];

        // ---- S^T = K * Q^T over 64 dims
        floatx16 sacc = (floatx16)0.0f;
        __builtin_amdgcn_s_setprio(1);
#pragma unroll
        for (int dc = 0; dc < 4; ++dc)
            sacc = __builtin_amdgcn_mfma_f32_32x32x16_bf16(kf[dc], qf[dc], sacc, 0, 0, 0);
        __builtin_amdgcn_s_setprio(0);

        // ---- p = exp2(s), raw HW instruction (masked keys: s = 0 -> p = 1, corrected later)
        float p[16];
#pragma unroll
        for (int r = 0; r < 16; ++r) p[r] = __builtin_amdgcn_exp2f(sacc[r]);

        // ---- pack f32 P -> bf16 PV A-frags in-register
        const unsigned pk_a = cvt_pk_bf16(p[0],  p[1]);
        const unsigned pk_b = cvt_pk_bf16(p[2],  p[3]);
        const unsigned pk_c = cvt_pk_bf16(p[4],  p[5]);
        const unsigned pk_d = cvt_pk_bf16(p[6],  p[7]);
        const unsigned pk_e = cvt_pk_bf16(p[8],  p[9]);
        const unsigned pk_f = cvt_pk_bf16(p[10], p[11]);
        const unsigned pk_g = cvt_pk_bf16(p[12], p[13]);
        const unsigned pk_h = cvt_pk_bf16(p[14], p[15]);
        const uintx2 s1 = __builtin_amdgcn_permlane32_swap(pk_a, pk_c, false, false);
        const uintx2 s2 = __builtin_amdgcn_permlane32_swap(pk_b, pk_d, false, false);
        const uintx2 s3 = __builtin_amdgcn_permlane32_swap(pk_e, pk_g, false, false);
        const uintx2 s4 = __builtin_amdgcn_permlane32_swap(pk_f, pk_h, false, false);
        const short8 pf0 = mk_pf(s1, s2);   // keys ks*32 + 0..15
        const short8 pf1 = mk_pf(s3, s4);   // keys ks*32 + 16..31

        // ---- rowsum via ones-MFMA + PV from LDS V^T (masked V rows are zero)
        __builtin_amdgcn_s_setprio(1);
        lacc = __builtin_amdgcn_mfma_f32_32x32x16_bf16(pf0, ones, lacc, 0, 0, 0);
        lacc = __builtin_amdgcn_mfma_f32_32x32x16_bf16(pf1, ones, lacc, 0, 0, 0);
#pragma unroll
        for (int dn = 0; dn < 2; ++dn) {
            const short8 vf0 = *(const short8*)&KVlds[2 + cur][dn * 32 + ll][ks * 32 + hi * 8];
            const short8 vf1 = *(const short8*)&KVlds[2 + cur][dn * 32 + ll][ks * 32 + 16 + hi * 8];
            oacc[dn] = __builtin_amdgcn_mfma_f32_32x32x16_bf16(pf0, vf0, oacc[dn], 0, 0, 0);
            oacc[dn] = __builtin_amdgcn_mfma_f32_32x32x16_bf16(pf1, vf1, oacc[dn], 0, 0, 0);
        }
        __builtin_amdgcn_s_setprio(0);

        if (kt + 1 < NT) {
            const int nxt = cur ^ 1;
            *(short8*)&KVlds[nxt][srow][sp8]     = kr;
            *(short8*)&KVlds[2 + nxt][srow][sp8] = vr;
        }
    }

    // ---- combine key-split partials (ks=1 -> ks=0) via LDS aliased over KVlds.
    float* Cmb = (float*)&KVlds[0][0][0];
#pragma unroll
    for (int ph = 0; ph < 2; ++ph) {
        __syncthreads();
        if (ks == 1 && (qh >> 1) == ph) {
            const int sl = qh & 1;
#pragma unroll
            for (int dn = 0; dn < 2; ++dn)
#pragma unroll
                for (int r = 0; r < 16; ++r)
                    Cmb[((sl * 2 + dn) * 16 + r) * 64 + lane] = oacc[dn][r];
#pragma unroll
            for (int r = 0; r < 16; ++r)
                Cmb[4096 + (sl * 16 + r) * 64 + lane] = lacc[r];
        }
        __syncthreads();
        if (ks == 0 && (qh >> 1) == ph) {
            const int sl = qh & 1;
#pragma unroll
            for (int dn = 0; dn < 2; ++dn)
#pragma unroll
                for (int r = 0; r < 16; ++r)
                    oacc[dn][r] += Cmb[((sl * 2 + dn) * 16 + r) * 64 + lane];
#pragma unroll
            for (int r = 0; r < 16; ++r)
                lacc[r] += Cmb[4096 + (sl * 16 + r) * 64 + lane];
        }
    }

    // ---- epilogue (ks=0 waves): subtract masked count, normalize, write bf16 [B,S,D]
    if (ks == 0) {
        const int h = bh & 15;
        const float nmf = (float)(SS - (Wsum[0] + Wsum[1] + Wsum[2] + Wsum[3]
                                      + Wsum[4] + Wsum[5] + Wsum[6] + Wsum[7]));
        float linv[16];
#pragma unroll
        for (int r = 0; r < 16; ++r) linv[r] = 1.0f / (lacc[r] - nmf);
#pragma unroll
        for (int dn = 0; dn < 2; ++dn)
#pragma unroll
            for (int r = 0; r < 16; ++r) {
                const int q = q0 + qh * 32 + (r & 3) + 8 * (r >> 2) + 4 * hi;
                Ob[(size_t)(b * SS + q) * DD + h * HD + dn * 32 + ll] =
                    f2bf_rne(oacc[dn][r] * linv[r]);
            }
    }
}

// ---------------- O-projection GEMM: 128x64 tile, gload_lds, XCD-chunked grid 512 ----------------
__global__ __launch_bounds__(256, 3)
void o_gemm(const ushort* __restrict__ A, const ushort* __restrict__ B,
            const float* __restrict__ bias, float* __restrict__ out)
{
    __shared__ __align__(16) ushort sA[128][32];
    __shared__ __align__(16) ushort sB[64][32];

    const int tid  = threadIdx.x;
    const int lane = tid & 63;
    const int wave = tid >> 6;
    const int wr = wave >> 1;     // m half (64 rows)
    const int wc = wave & 1;      // n half (32 cols)
    const int lt = lane & 15;
    const int lq = lane >> 4;

    // bijective XCD-chunk swizzle (512 % 8 == 0): same-m n-blocks share an XCD
    const int wg = (blockIdx.x & 7) * 64 + (blockIdx.x >> 3);
    const int m0 = (wg >> 4) * 128;   // 32 m-blocks
    const int n0 = (wg & 15) * 64;    // 16 n-blocks

    floatx4 acc[4][2];
#pragma unroll
    for (int mi = 0; mi < 4; ++mi)
#pragma unroll
        for (int ni = 0; ni < 2; ++ni) acc[mi][ni] = (floatx4)0.0f;

    const int srow = tid >> 2;          // 0..63
    const int sc   = (tid & 3) << 3;    // 0,8,16,24
    const ushort* gA0 = A + (size_t)(m0 + srow) * DD + sc;
    const ushort* gA1 = A + (size_t)(m0 + 64 + srow) * DD + sc;
    const ushort* gB0 = B + (size_t)(n0 + srow) * DD + sc;

    for (int k0 = 0; k0 < DD; k0 += 32) {
        __syncthreads();
        GLD16(gA0 + k0, &sA[srow][sc]);
        GLD16(gA1 + k0, &sA[64 + srow][sc]);
        GLD16(gB0 + k0, &sB[srow][sc]);
        __syncthreads();

        short8 af[4], bf_[2];
#pragma unroll
        for (int mi = 0; mi < 4; ++mi)
            af[mi] = *(const short8*)&sA[wr * 64 + mi * 16 + lt][lq * 8];
#pragma unroll
        for (int ni = 0; ni < 2; ++ni)
            bf_[ni] = *(const short8*)&sB[wc * 32 + ni * 16 + lt][lq * 8];

#pragma unroll
        for (int mi = 0; mi < 4; ++mi)
#pragma unroll
            for (int ni = 0; ni < 2; ++ni)
                acc[mi][ni] = __builtin_amdgcn_mfma_f32_16x16x32_bf16(af[mi], bf_[ni], acc[mi][ni], 0, 0, 0);
    }

#pragma unroll
    for (int mi = 0; mi < 4; ++mi)
#pragma unroll
        for (int ni = 0; ni < 2; ++ni) {
            const int n = n0 + wc * 32 + ni * 16 + lt;
            const float bb = bias[n];
#pragma unroll
            for (int r = 0; r < 4; ++r) {
                const int m = m0 + wr * 64 + mi * 16 + lq * 4 + r;
                out[(size_t)m * DD + n] = acc[mi][ni][r] + bb;
            }
        }
}

extern "C" void kernel_launch(void* const* d_in, const int* in_sizes, int n_in,
                              void* d_out, int out_size, void* d_ws, size_t ws_size,
                              hipStream_t stream) {
    const float* xq   = (const float*)d_in[0];
    const float* xk   = (const float*)d_in[1];
    const float* xv   = (const float*)d_in[2];
    const int*   mask = (const int*)d_in[3];
    const float* wq   = (const float*)d_in[4];
    const float* bq   = (const float*)d_in[5];
    const float* wk   = (const float*)d_in[6];
    const float* bk   = (const float*)d_in[7];
    const float* wv   = (const float*)d_in[8];
    const float* bv   = (const float*)d_in[9];
    const float* wo   = (const float*)d_in[10];
    const float* bo   = (const float*)d_in[11];
    float* out = (float*)d_out;

    const size_t n = (size_t)BB * SS * DD;   // 4,194,304 elements
    const size_t w1 = (size_t)DD * DD;       // 1,048,576

    // ws (42 MB): Xq 8, Xk 8, Xv 8, Kb 8, Vt 8, Wo 2.
    // Ob aliases Xqb (Xq consumed by qkv_gemm z=0 before attn writes it).
    ushort* Xqb = (ushort*)d_ws;
    ushort* Xkb = Xqb + n;
    ushort* Xvb = Xkb + n;
    ushort* Kb  = Xvb + n;
    ushort* Vt  = Kb + n;
    ushort* Wob = Vt + n;
    ushort* Ob  = Xqb;

    // d_out (16 MB): Qb [0,8MB); Wq/Wk/Wv bf16 [8,14MB) — dead before o_gemm.
    ushort* Qb  = (ushort*)out;
    ushort* Wqb = Qb + n;
    ushort* Wkb = Wqb + w1;
    ushort* Wvb = Wkb + w1;

    const float qscale = 0.125f * 1.44269504088896340736f;   // /sqrt(HD) * log2(e)

    dim3 gc(2048, 1, 4);
    convert_bf16<<<gc, 256, 0, stream>>>(xq, xk, xv, wq, wk, wv, wo,
                                         Xqb, Xkb, Xvb, Wqb, Wkb, Wvb, Wob);

    qkv_gemm<<<dim3(768), 256, 0, stream>>>(Xqb, Xkb, Xvb, Wqb, Wkb, Wvb,
                                            bq, bk, bv, mask, Qb, Kb, Vt, qscale);

    attn_mfma<<<dim3(512), 512, 0, stream>>>(Qb, Kb, Vt, mask, Ob);

    o_gemm<<<dim3(512), 256, 0, stream>>>(Ob, Wob, bo, out);
}

// Round 10
// 208.742 us; speedup vs baseline: 1.1938x; 1.0190x over previous
//
#include <hip/hip_runtime.h>
#include <math.h>

#define BB 2
#define SS 2048
#define DD 1024
#define HH 16
#define HD 64

typedef short short8 __attribute__((ext_vector_type(8)));
typedef float floatx4 __attribute__((ext_vector_type(4)));
typedef float floatx16 __attribute__((ext_vector_type(16)));
typedef unsigned int uintx2 __attribute__((ext_vector_type(2)));

__device__ inline ushort f2bf_rne(float x) {
    union { float f; unsigned u; } v; v.f = x;
    unsigned r = v.u + 0x7FFFu + ((v.u >> 16) & 1u);
    return (ushort)(r >> 16);
}
__device__ inline unsigned cvt_pk_bf16(float lo, float hi) {
    unsigned r;
    asm("v_cvt_pk_bf16_f32 %0, %1, %2" : "=v"(r) : "v"(lo), "v"(hi));
    return r;
}
// assemble PV A-frag from two permlane32_swap results: [x.lo, y.lo, x.hi, y.hi]
__device__ inline short8 mk_pf(uintx2 x, uintx2 y) {
    union { unsigned u[4]; short8 s; } t;
    t.u[0] = x[0]; t.u[1] = y[0]; t.u[2] = x[1]; t.u[3] = y[1];
    return t.s;
}

// async global -> LDS DMA, 16 B per lane (dest must be wave-linear: base + lane*16)
#define GLD16(gp, lp) __builtin_amdgcn_global_load_lds( \
    (const __attribute__((address_space(1))) void*)(gp), \
    (__attribute__((address_space(3))) void*)(lp), 16, 0, 0)

// ---------------- streaming fp32 -> bf16 conversion ----------------
// Separate kernel is MEASURED-faster than fusing into the GEMMs (R6 217.6 vs
// R7/R8 244-249): bf16 staging lets the GEMMs use global_load_lds async DMA.
__global__ __launch_bounds__(256)
void convert_bf16(const float* __restrict__ xq, const float* __restrict__ xk,
                  const float* __restrict__ xv,
                  const float* __restrict__ wq, const float* __restrict__ wk,
                  const float* __restrict__ wv, const float* __restrict__ wo,
                  ushort* __restrict__ Xq, ushort* __restrict__ Xk,
                  ushort* __restrict__ Xv,
                  ushort* __restrict__ Wq, ushort* __restrict__ Wk,
                  ushort* __restrict__ Wv, ushort* __restrict__ Wo)
{
    const int z = blockIdx.z;
    const size_t i = ((size_t)blockIdx.x * 256 + threadIdx.x) * 8;

    const float* src;
    ushort* dst;
    size_t off;
    if (z < 3) {
        src = (z == 0) ? xq : (z == 1) ? xk : xv;
        dst = (z == 0) ? Xq : (z == 1) ? Xk : Xv;
        off = i;
    } else {
        const int seg = (int)(i >> 20);
        off = i & ((1u << 20) - 1);
        src = (seg == 0) ? wq : (seg == 1) ? wk : (seg == 2) ? wv : wo;
        dst = (seg == 0) ? Wq : (seg == 1) ? Wk : (seg == 2) ? Wv : Wo;
    }
    float x[8];
    *(float4*)&x[0] = *(const float4*)(src + off);
    *(float4*)&x[4] = *(const float4*)(src + off + 4);
    short8 h8;
#pragma unroll
    for (int j = 0; j < 8; ++j) h8[j] = (short)f2bf_rne(x[j]);
    *(short8*)&dst[off] = h8;
}

// ---------------- QKV GEMM: 128x128, gload_lds, BK=64 (2 buffers / barrier) ----------------
// Two LDS buffer pairs staged per barrier pair -> 16 vmcnt(0) drains instead of
// 32 (the drain convoy was the measured stall: MfmaUtil 20% vs 11 us MFMA floor
// at ~43 us wall). Read/write patterns per buffer identical to the proven R9
// code. XCD-chunked 1-D grid 768 keeps A row-panels in one L2.
__global__ __launch_bounds__(256, 3)
void qkv_gemm(const ushort* __restrict__ Xq, const ushort* __restrict__ Xk,
              const ushort* __restrict__ Xv,
              const ushort* __restrict__ Wq, const ushort* __restrict__ Wk,
              const ushort* __restrict__ Wv,
              const float* __restrict__ bq, const float* __restrict__ bk,
              const float* __restrict__ bv, const int* __restrict__ mask,
              ushort* __restrict__ Qo, ushort* __restrict__ Ko,
              ushort* __restrict__ Vo, float qscale)
{
    __shared__ __align__(16) ushort Alds[2][128][32];
    __shared__ __align__(16) ushort Blds[2][128][32];

    const int tid = threadIdx.x;

    // bijective XCD-chunk swizzle (768 % 8 == 0)
    const int wg  = (blockIdx.x & 7) * 96 + (blockIdx.x >> 3);
    const int z   = wg >> 8;            // 0..2
    const int rem = wg & 255;
    const int m0  = (rem >> 3) * 128;   // 32 m-blocks
    const int n0  = (rem & 7) * 128;    // 8 n-blocks

    const ushort* X    = (z == 0) ? Xq : (z == 1) ? Xk : Xv;
    const ushort* W    = (z == 0) ? Wq : (z == 1) ? Wk : Wv;
    const float*  bias = (z == 0) ? bq : (z == 1) ? bk : bv;
    const float   osc  = (z == 0) ? qscale : 1.0f;

    const int lane = tid & 63;
    const int wave = tid >> 6;
    const int wr = wave >> 1;
    const int wc = wave & 1;
    const int lt = lane & 15;
    const int lq = lane >> 4;

    floatx4 acc[4][4];
#pragma unroll
    for (int mi = 0; mi < 4; ++mi)
#pragma unroll
        for (int ni = 0; ni < 4; ++ni) acc[mi][ni] = (floatx4)0.0f;

    const int srow = tid >> 2;          // 0..63
    const int sc   = (tid & 3) << 3;    // ushort col: 0,8,16,24
    const ushort* gA0 = X + (size_t)(m0 + srow) * DD + sc;
    const ushort* gA1 = X + (size_t)(m0 + 64 + srow) * DD + sc;
    const ushort* gB0 = W + (size_t)(n0 + srow) * DD + sc;
    const ushort* gB1 = W + (size_t)(n0 + 64 + srow) * DD + sc;

    for (int k0 = 0; k0 < DD; k0 += 64) {
        __syncthreads();
#pragma unroll
        for (int h = 0; h < 2; ++h) {
            GLD16(gA0 + k0 + h * 32, &Alds[h][srow][sc]);
            GLD16(gA1 + k0 + h * 32, &Alds[h][64 + srow][sc]);
            GLD16(gB0 + k0 + h * 32, &Blds[h][srow][sc]);
            GLD16(gB1 + k0 + h * 32, &Blds[h][64 + srow][sc]);
        }
        __syncthreads();

#pragma unroll
        for (int h = 0; h < 2; ++h) {
            short8 af[4], bf_[4];
#pragma unroll
            for (int mi = 0; mi < 4; ++mi)
                af[mi] = *(const short8*)&Alds[h][wr * 64 + mi * 16 + lt][lq * 8];
#pragma unroll
            for (int ni = 0; ni < 4; ++ni)
                bf_[ni] = *(const short8*)&Blds[h][wc * 64 + ni * 16 + lt][lq * 8];

#pragma unroll
            for (int mi = 0; mi < 4; ++mi)
#pragma unroll
                for (int ni = 0; ni < 4; ++ni)
                    acc[mi][ni] = __builtin_amdgcn_mfma_f32_16x16x32_bf16(af[mi], bf_[ni], acc[mi][ni], 0, 0, 0);
        }
    }

    float bbv[4];
#pragma unroll
    for (int ni = 0; ni < 4; ++ni) bbv[ni] = bias[n0 + wc * 64 + ni * 16 + lt];

    if (z == 2) {
        // V^T write, masked key rows zeroed so attention PV needs no mask.
#pragma unroll
        for (int mi = 0; mi < 4; ++mi) {
            const int mb  = m0 + wr * 64 + mi * 16 + lq * 4;
            const int bb_ = mb >> 11;
            const int s   = mb & (SS - 1);
            const int4 mm = *(const int4*)(mask + bb_ * SS + s);
            const float mf0 = (float)mm.x, mf1 = (float)mm.y;
            const float mf2 = (float)mm.z, mf3 = (float)mm.w;
#pragma unroll
            for (int ni = 0; ni < 4; ++ni) {
                const int n = n0 + wc * 64 + ni * 16 + lt;
                const int h = n >> 6;
                ushort4 pack;
                pack.x = f2bf_rne((acc[mi][ni][0] + bbv[ni]) * mf0);
                pack.y = f2bf_rne((acc[mi][ni][1] + bbv[ni]) * mf1);
                pack.z = f2bf_rne((acc[mi][ni][2] + bbv[ni]) * mf2);
                pack.w = f2bf_rne((acc[mi][ni][3] + bbv[ni]) * mf3);
                *(ushort4*)&Vo[(size_t)((bb_ * HH + h) * HD + (n & 63)) * SS + s] = pack;
            }
        }
    } else {
        // Q (scaled) or K (masked rows zeroed -> s=0 -> p=1, corrected in attn epilogue)
        ushort* C = z ? Ko : Qo;
#pragma unroll
        for (int mi = 0; mi < 4; ++mi) {
            const int mb  = m0 + wr * 64 + mi * 16 + lq * 4;
            const int bb_ = mb >> 11;
            const int s   = mb & (SS - 1);
            float mf[4] = {1.0f, 1.0f, 1.0f, 1.0f};
            if (z == 1) {
                const int4 mm = *(const int4*)(mask + bb_ * SS + s);
                mf[0] = (float)mm.x; mf[1] = (float)mm.y;
                mf[2] = (float)mm.z; mf[3] = (float)mm.w;
            }
#pragma unroll
            for (int ni = 0; ni < 4; ++ni) {
                const int n = n0 + wc * 64 + ni * 16 + lt;
                const int h = n >> 6;
#pragma unroll
                for (int r = 0; r < 4; ++r) {
                    C[(size_t)((bb_ * HH + h) * SS + (s + r)) * HD + (n & 63)] =
                        f2bf_rne((acc[mi][ni][r] + bbv[ni]) * osc * mf[r]);
                }
            }
        }
    }
}

// ---------------- MFMA flash attention: 8 waves, 128-row q-block, 128-key tiles ----------------
// 128-key K/V tiles (two 64-key subtiles per barrier) -> 16 barriers instead of
// 32. At 44 us both MFMA (39%) and VALU (38%) sat at their floor shares: the
// barrier convergence of 8-wave groups was the serializer. Swapped QK^T 32x32,
// in-register softmax, mask pre-folded, raw v_exp_f32, setprio on MFMA clusters.
__global__ __launch_bounds__(512, 4)
void attn_mfma(const ushort* __restrict__ Qb, const ushort* __restrict__ Kb,
               const ushort* __restrict__ Vt, const int* __restrict__ mask,
               ushort* __restrict__ Ob)
{
    __shared__ __align__(16) ushort Klds[2][128][68];   // [key][dim], dbuf
    __shared__ __align__(16) ushort Vlds[2][64][136];   // [dim][key], dbuf
    __shared__ int Wsum[8];

    const int tid  = threadIdx.x;
    const int lane = tid & 63;
    const int wave = tid >> 6;     // 0..7
    const int ll   = lane & 31;
    const int hi   = lane >> 5;
    const int qh   = wave & 3;     // q-group owned (32 rows)
    const int ks   = wave >> 2;    // key sub-tile owned (32 keys of each 64-half)

    // XCD-locality swizzle (perf heuristic; any bid->XCD mapping stays correct)
    const int bid    = blockIdx.x;
    const int xcd    = bid & 7;
    const int slot   = bid >> 3;          // 0..63
    const int bhloc  = slot >> 4;         // 0..3
    const int qi     = slot & 15;         // 0..15
    const int bh     = xcd * 4 + bhloc;   // 0..31
    const int b      = bh >> 4;
    const int q0     = qi * 128;

    const size_t sbase = (size_t)bh * SS * HD;
    const size_t vbase = (size_t)bh * HD * SS;

    // masked-key count for the denominator correction (exact integer)
    {
        const int4 ma = *(const int4*)(mask + b * SS + tid * 4);
        int s = ma.x + ma.y + ma.z + ma.w;
#pragma unroll
        for (int w = 32; w >= 1; w >>= 1) s += __shfl_xor(s, w);
        if (lane == 0) Wsum[wave] = s;
    }

    short8 ones;
#pragma unroll
    for (int j = 0; j < 8; ++j) ones[j] = (short)0x3F80;   // bf16 1.0

    // Q B-frags for this wave's 32 q-rows: 4 dim-chunks, held in regs
    short8 qf[4];
    {
        const size_t qrow = sbase + (size_t)(q0 + qh * 32 + ll) * HD;
#pragma unroll
        for (int dc = 0; dc < 4; ++dc)
            qf[dc] = *(const short8*)(Qb + qrow + dc * 16 + hi * 8);
    }

    floatx16 oacc[2];
    oacc[0] = (floatx16)0.0f;
    oacc[1] = (floatx16)0.0f;
    floatx16 lacc = (floatx16)0.0f;

    // K staging: 128 rows x 64 dims: row = tid>>2, dim col = (tid&3)*16 (2 short8)
    // V staging: 64 dims x 128 keys: dim = tid>>3, key col = (tid&7)*16 (2 short8)
    const int krow = tid >> 2;
    const int kcol = (tid & 3) << 4;
    const int vrow = tid >> 3;
    const int vcol = (tid & 7) << 4;

    short8 kr0, kr1, vr0, vr1;

    {   // prologue: tile 0 (128 keys)
        const size_t koff = sbase + (size_t)krow * HD + kcol;
        kr0 = *(const short8*)(Kb + koff);
        kr1 = *(const short8*)(Kb + koff + 8);
        const size_t voff = vbase + (size_t)vrow * SS + vcol;
        vr0 = *(const short8*)(Vt + voff);
        vr1 = *(const short8*)(Vt + voff + 8);
        *(short8*)&Klds[0][krow][kcol]     = kr0;
        *(short8*)&Klds[0][krow][kcol + 8] = kr1;
        *(short8*)&Vlds[0][vrow][vcol]     = vr0;
        *(short8*)&Vlds[0][vrow][vcol + 8] = vr1;
    }

    const int NT = SS / 128;
    for (int kt = 0; kt < NT; ++kt) {
        const int cur = kt & 1;
        __syncthreads();

        if (kt + 1 < NT) {
            const int k0n = (kt + 1) * 128;
            const size_t koff = sbase + (size_t)(k0n + krow) * HD + kcol;
            kr0 = *(const short8*)(Kb + koff);
            kr1 = *(const short8*)(Kb + koff + 8);
            const size_t voff = vbase + (size_t)vrow * SS + k0n + vcol;
            vr0 = *(const short8*)(Vt + voff);
            vr1 = *(const short8*)(Vt + voff + 8);
        }

#pragma unroll
        for (int sub = 0; sub < 2; ++sub) {
            // ---- this wave's 32-key sub-tile K-frags
            short8 kf[4];
#pragma unroll
            for (int dc = 0; dc < 4; ++dc)
                kf[dc] = *(const short8*)&Klds[cur][sub * 64 + ks * 32 + ll][dc * 16 + hi * 8];

            // ---- S^T = K * Q^T over 64 dims
            floatx16 sacc = (floatx16)0.0f;
            __builtin_amdgcn_s_setprio(1);
#pragma unroll
            for (int dc = 0; dc < 4; ++dc)
                sacc = __builtin_amdgcn_mfma_f32_32x32x16_bf16(kf[dc], qf[dc], sacc, 0, 0, 0);
            __builtin_amdgcn_s_setprio(0);

            // ---- p = exp2(s) (masked keys: s = 0 -> p = 1, corrected in epilogue)
            float p[16];
#pragma unroll
            for (int r = 0; r < 16; ++r) p[r] = __builtin_amdgcn_exp2f(sacc[r]);

            // ---- pack f32 P -> bf16 PV A-frags in-register
            const unsigned pk_a = cvt_pk_bf16(p[0],  p[1]);
            const unsigned pk_b = cvt_pk_bf16(p[2],  p[3]);
            const unsigned pk_c = cvt_pk_bf16(p[4],  p[5]);
            const unsigned pk_d = cvt_pk_bf16(p[6],  p[7]);
            const unsigned pk_e = cvt_pk_bf16(p[8],  p[9]);
            const unsigned pk_f = cvt_pk_bf16(p[10], p[11]);
            const unsigned pk_g = cvt_pk_bf16(p[12], p[13]);
            const unsigned pk_h = cvt_pk_bf16(p[14], p[15]);
            const uintx2 s1 = __builtin_amdgcn_permlane32_swap(pk_a, pk_c, false, false);
            const uintx2 s2 = __builtin_amdgcn_permlane32_swap(pk_b, pk_d, false, false);
            const uintx2 s3 = __builtin_amdgcn_permlane32_swap(pk_e, pk_g, false, false);
            const uintx2 s4 = __builtin_amdgcn_permlane32_swap(pk_f, pk_h, false, false);
            const short8 pf0 = mk_pf(s1, s2);   // keys sub*64 + ks*32 + 0..15
            const short8 pf1 = mk_pf(s3, s4);   // keys sub*64 + ks*32 + 16..31

            // ---- rowsum via ones-MFMA + PV from LDS V^T (masked V rows are zero)
            __builtin_amdgcn_s_setprio(1);
            lacc = __builtin_amdgcn_mfma_f32_32x32x16_bf16(pf0, ones, lacc, 0, 0, 0);
            lacc = __builtin_amdgcn_mfma_f32_32x32x16_bf16(pf1, ones, lacc, 0, 0, 0);
#pragma unroll
            for (int dn = 0; dn < 2; ++dn) {
                const short8 vf0 = *(const short8*)&Vlds[cur][dn * 32 + ll][sub * 64 + ks * 32 + hi * 8];
                const short8 vf1 = *(const short8*)&Vlds[cur][dn * 32 + ll][sub * 64 + ks * 32 + 16 + hi * 8];
                oacc[dn] = __builtin_amdgcn_mfma_f32_32x32x16_bf16(pf0, vf0, oacc[dn], 0, 0, 0);
                oacc[dn] = __builtin_amdgcn_mfma_f32_32x32x16_bf16(pf1, vf1, oacc[dn], 0, 0, 0);
            }
            __builtin_amdgcn_s_setprio(0);
        }

        if (kt + 1 < NT) {
            const int nxt = cur ^ 1;
            *(short8*)&Klds[nxt][krow][kcol]     = kr0;
            *(short8*)&Klds[nxt][krow][kcol + 8] = kr1;
            *(short8*)&Vlds[nxt][vrow][vcol]     = vr0;
            *(short8*)&Vlds[nxt][vrow][vcol + 8] = vr1;
        }
    }

    // ---- combine key-split partials (ks=1 -> ks=0) via LDS aliased over Klds.
    float* Cmb = (float*)&Klds[0][0][0];
#pragma unroll
    for (int ph = 0; ph < 2; ++ph) {
        __syncthreads();
        if (ks == 1 && (qh >> 1) == ph) {
            const int sl = qh & 1;
#pragma unroll
            for (int dn = 0; dn < 2; ++dn)
#pragma unroll
                for (int r = 0; r < 16; ++r)
                    Cmb[((sl * 2 + dn) * 16 + r) * 64 + lane] = oacc[dn][r];
#pragma unroll
            for (int r = 0; r < 16; ++r)
                Cmb[4096 + (sl * 16 + r) * 64 + lane] = lacc[r];
        }
        __syncthreads();
        if (ks == 0 && (qh >> 1) == ph) {
            const int sl = qh & 1;
#pragma unroll
            for (int dn = 0; dn < 2; ++dn)
#pragma unroll
                for (int r = 0; r < 16; ++r)
                    oacc[dn][r] += Cmb[((sl * 2 + dn) * 16 + r) * 64 + lane];
#pragma unroll
            for (int r = 0; r < 16; ++r)
                lacc[r] += Cmb[4096 + (sl * 16 + r) * 64 + lane];
        }
    }

    // ---- epilogue (ks=0 waves): subtract masked count, normalize, write bf16 [B,S,D]
    if (ks == 0) {
        const int h = bh & 15;
        const float nmf = (float)(SS - (Wsum[0] + Wsum[1] + Wsum[2] + Wsum[3]
                                      + Wsum[4] + Wsum[5] + Wsum[6] + Wsum[7]));
        float linv[16];
#pragma unroll
        for (int r = 0; r < 16; ++r) linv[r] = 1.0f / (lacc[r] - nmf);
#pragma unroll
        for (int dn = 0; dn < 2; ++dn)
#pragma unroll
            for (int r = 0; r < 16; ++r) {
                const int q = q0 + qh * 32 + (r & 3) + 8 * (r >> 2) + 4 * hi;
                Ob[(size_t)(b * SS + q) * DD + h * HD + dn * 32 + ll] =
                    f2bf_rne(oacc[dn][r] * linv[r]);
            }
    }
}

// ---------------- O-projection GEMM: 128x64 tile, gload_lds, XCD-chunked grid 512 ----------------
__global__ __launch_bounds__(256, 3)
void o_gemm(const ushort* __restrict__ A, const ushort* __restrict__ B,
            const float* __restrict__ bias, float* __restrict__ out)
{
    __shared__ __align__(16) ushort sA[2][128][32];
    __shared__ __align__(16) ushort sB[2][64][32];

    const int tid  = threadIdx.x;
    const int lane = tid & 63;
    const int wave = tid >> 6;
    const int wr = wave >> 1;     // m half (64 rows)
    const int wc = wave & 1;      // n half (32 cols)
    const int lt = lane & 15;
    const int lq = lane >> 4;

    // bijective XCD-chunk swizzle (512 % 8 == 0): same-m n-blocks share an XCD
    const int wg = (blockIdx.x & 7) * 64 + (blockIdx.x >> 3);
    const int m0 = (wg >> 4) * 128;   // 32 m-blocks
    const int n0 = (wg & 15) * 64;    // 16 n-blocks

    floatx4 acc[4][2];
#pragma unroll
    for (int mi = 0; mi < 4; ++mi)
#pragma unroll
        for (int ni = 0; ni < 2; ++ni) acc[mi][ni] = (floatx4)0.0f;

    const int srow = tid >> 2;          // 0..63
    const int sc   = (tid & 3) << 3;    // 0,8,16,24
    const ushort* gA0 = A + (size_t)(m0 + srow) * DD + sc;
    const ushort* gA1 = A + (size_t)(m0 + 64 + srow) * DD + sc;
    const ushort* gB0 = B + (size_t)(n0 + srow) * DD + sc;

    for (int k0 = 0; k0 < DD; k0 += 64) {
        __syncthreads();
#pragma unroll
        for (int h = 0; h < 2; ++h) {
            GLD16(gA0 + k0 + h * 32, &sA[h][srow][sc]);
            GLD16(gA1 + k0 + h * 32, &sA[h][64 + srow][sc]);
            GLD16(gB0 + k0 + h * 32, &sB[h][srow][sc]);
        }
        __syncthreads();

#pragma unroll
        for (int h = 0; h < 2; ++h) {
            short8 af[4], bf_[2];
#pragma unroll
            for (int mi = 0; mi < 4; ++mi)
                af[mi] = *(const short8*)&sA[h][wr * 64 + mi * 16 + lt][lq * 8];
#pragma unroll
            for (int ni = 0; ni < 2; ++ni)
                bf_[ni] = *(const short8*)&sB[h][wc * 32 + ni * 16 + lt][lq * 8];

#pragma unroll
            for (int mi = 0; mi < 4; ++mi)
#pragma unroll
                for (int ni = 0; ni < 2; ++ni)
                    acc[mi][ni] = __builtin_amdgcn_mfma_f32_16x16x32_bf16(af[mi], bf_[ni], acc[mi][ni], 0, 0, 0);
        }
    }

#pragma unroll
    for (int mi = 0; mi < 4; ++mi)
#pragma unroll
        for (int ni = 0; ni < 2; ++ni) {
            const int n = n0 + wc * 32 + ni * 16 + lt;
            const float bb = bias[n];
#pragma unroll
            for (int r = 0; r < 4; ++r) {
                const int m = m0 + wr * 64 + mi * 16 + lq * 4 + r;
                out[(size_t)m * DD + n] = acc[mi][ni][r] + bb;
            }
        }
}

extern "C" void kernel_launch(void* const* d_in, const int* in_sizes, int n_in,
                              void* d_out, int out_size, void* d_ws, size_t ws_size,
                              hipStream_t stream) {
    const float* xq   = (const float*)d_in[0];
    const float* xk   = (const float*)d_in[1];
    const float* xv   = (const float*)d_in[2];
    const int*   mask = (const int*)d_in[3];
    const float* wq   = (const float*)d_in[4];
    const float* bq   = (const float*)d_in[5];
    const float* wk   = (const float*)d_in[6];
    const float* bk   = (const float*)d_in[7];
    const float* wv   = (const float*)d_in[8];
    const float* bv   = (const float*)d_in[9];
    const float* wo   = (const float*)d_in[10];
    const float* bo   = (const float*)d_in[11];
    float* out = (float*)d_out;

    const size_t n = (size_t)BB * SS * DD;   // 4,194,304 elements
    const size_t w1 = (size_t)DD * DD;       // 1,048,576

    // ws (42 MB): Xq 8, Xk 8, Xv 8, Kb 8, Vt 8, Wo 2.
    // Ob aliases Xqb (Xq consumed by qkv_gemm z=0 before attn writes it).
    ushort* Xqb = (ushort*)d_ws;
    ushort* Xkb = Xqb + n;
    ushort* Xvb = Xkb + n;
    ushort* Kb  = Xvb + n;
    ushort* Vt  = Kb + n;
    ushort* Wob = Vt + n;
    ushort* Ob  = Xqb;

    // d_out (16 MB): Qb [0,8MB); Wq/Wk/Wv bf16 [8,14MB) — dead before o_gemm.
    ushort* Qb  = (ushort*)out;
    ushort* Wqb = Qb + n;
    ushort* Wkb = Wqb + w1;
    ushort* Wvb = Wkb + w1;

    const float qscale = 0.125f * 1.44269504088896340736f;   // /sqrt(HD) * log2(e)

    dim3 gc(2048, 1, 4);
    convert_bf16<<<gc, 256, 0, stream>>>(xq, xk, xv, wq, wk, wv, wo,
                                         Xqb, Xkb, Xvb, Wqb, Wkb, Wvb, Wob);

    qkv_gemm<<<dim3(768), 256, 0, stream>>>(Xqb, Xkb, Xvb, Wqb, Wkb, Wvb,
                                            bq, bk, bv, mask, Qb, Kb, Vt, qscale);

    attn_mfma<<<dim3(512), 512, 0, stream>>>(Qb, Kb, Vt, mask, Ob);

    o_gemm<<<dim3(512), 256, 0, stream>>>(Ob, Wob, bo, out);
}